// Round 2
// baseline (531.911 us; speedup 1.0000x reference)
//
#include <hip/hip_runtime.h>
#include <hip/hip_bf16.h>
#include <stdint.h>

#define B_ 32
#define S_ 577
#define D_ 768
#define H_ 12
#define FF_ 3072
#define MROWS (B_*S_)   // 18464

typedef __attribute__((ext_vector_type(8))) short sh8;
typedef __attribute__((ext_vector_type(4))) float f32x4;
typedef __attribute__((ext_vector_type(4))) unsigned short us4;

static __device__ __forceinline__ unsigned short f2b(float f) {
  __hip_bfloat16 h = __float2bfloat16(f);
  return *reinterpret_cast<unsigned short*>(&h);
}
static __device__ __forceinline__ float b2f(unsigned short u) {
  __hip_bfloat16 h;
  *reinterpret_cast<unsigned short*>(&h) = u;
  return __bfloat162float(h);
}

// Branch-free exact-GELU: 0.5*v*(1+erf(v/sqrt2)) with erf via A&S 7.1.26.
// |err(erf)| <= 1.5e-7 -> ~1e-7 output err, 5 orders below bf16 rounding.
static __device__ __forceinline__ float fast_gelu(float v) {
  const float z = fabsf(v) * 0.70710678118f;
  const float t = __builtin_amdgcn_rcpf(__builtin_fmaf(0.3275911f, z, 1.0f));
  float p = 1.061405429f;
  p = __builtin_fmaf(p, t, -1.453152027f);
  p = __builtin_fmaf(p, t,  1.421413741f);
  p = __builtin_fmaf(p, t, -0.284496736f);
  p = __builtin_fmaf(p, t,  0.254829592f);
  p = p * t;
  const float e = __expf(-z * z);
  const float erf_abs = __builtin_fmaf(-p, e, 1.0f);   // erf(|x|)
  const float erf_v = copysignf(erf_abs, v);
  const float hv = 0.5f * v;
  return __builtin_fmaf(hv, erf_v, hv);                // 0.5v*(1+erf)
}

#define GLOAD_LDS16(gp, lp) \
  __builtin_amdgcn_global_load_lds((const __attribute__((address_space(1))) unsigned int*)(gp), \
                                   (__attribute__((address_space(3))) unsigned int*)(lp), 16, 0, 0)

// ---------------------------------------------------------------------------
// Coalesced transpose-packs: fp32 [K][N] -> bf16 [N][K] via 64x64 LDS tiles
// ---------------------------------------------------------------------------
__global__ __launch_bounds__(256) void packT64(
    const float* __restrict__ src, unsigned short* __restrict__ dst, int K, int N)
{
  __shared__ unsigned short t[64][65];
  const int tid = threadIdx.x;
  const int c = tid & 63, r4 = tid >> 6;
  const int kb = blockIdx.y * 64, nb = blockIdx.x * 64;
#pragma unroll
  for (int p = 0; p < 16; ++p) {
    const int ko = p * 4 + r4;
    t[c][ko] = f2b(src[(size_t)(kb + ko) * N + nb + c]);
  }
  __syncthreads();
#pragma unroll
  for (int p = 0; p < 16; ++p) {
    const int rr = p * 4 + r4;
    dst[(size_t)(nb + rr) * K + kb + c] = t[rr][c];
  }
}

// per-head transpose for Wq/Wk/Wv [H][768][64] -> wT[(which*768+h*64+e)][768]
__global__ __launch_bounds__(256) void packQKV64(
    const float* __restrict__ Wq, const float* __restrict__ Wk, const float* __restrict__ Wv,
    unsigned short* __restrict__ dst)
{
  __shared__ unsigned short t[64][65];
  const int tid = threadIdx.x;
  const int c = tid & 63, r4 = tid >> 6;
  const int kb = blockIdx.x * 64;         // d tile (12)
  const int h = blockIdx.y;               // head (12)
  const int which = blockIdx.z;           // 0:q 1:k 2:v
  const float* src = ((which == 0) ? Wq : (which == 1) ? Wk : Wv) + (size_t)h * 768 * 64;
#pragma unroll
  for (int p = 0; p < 16; ++p) {
    const int ko = p * 4 + r4;
    t[c][ko] = f2b(src[(size_t)(kb + ko) * 64 + c]);
  }
  __syncthreads();
  unsigned short* db = dst + (size_t)(which * 768 + h * 64) * 768;
#pragma unroll
  for (int p = 0; p < 16; ++p) {
    const int rr = p * 4 + r4;            // e
    db[(size_t)rr * 768 + kb + c] = t[rr][c];
  }
}

__global__ __launch_bounds__(256) void bias_pack(
    const float* __restrict__ bq, const float* __restrict__ bk, const float* __restrict__ bv,
    float* __restrict__ biasq)
{
  const int idx = blockIdx.x * 256 + threadIdx.x;
  if (idx < 2304) {
    const int wb = idx / 768, rb = idx - wb * 768;
    const float* bb = (wb == 0) ? bq : (wb == 1) ? bk : bv;
    biasq[idx] = bb[rb];
  }
}

// ---------------------------------------------------------------------------
// LayerNorm fp32 -> bf16 (one 256-thread block per row of 768)
// ---------------------------------------------------------------------------
__global__ __launch_bounds__(256) void ln_bf16(
    const float* __restrict__ x, const float* __restrict__ w, const float* __restrict__ bse,
    unsigned short* __restrict__ out)
{
  const int row = blockIdx.x;
  const int tid = threadIdx.x;
  const float* xr = x + (size_t)row * 768;
  float v0 = xr[tid], v1 = xr[tid + 256], v2 = xr[tid + 512];
  float s = v0 + v1 + v2;
  float ss = v0 * v0 + v1 * v1 + v2 * v2;
#pragma unroll
  for (int off = 32; off >= 1; off >>= 1) {
    s  += __shfl_xor(s, off);
    ss += __shfl_xor(ss, off);
  }
  __shared__ float red[8];
  const int wv = tid >> 6, ln = tid & 63;
  if (ln == 0) { red[wv] = s; red[wv + 4] = ss; }
  __syncthreads();
  s  = red[0] + red[1] + red[2] + red[3];
  ss = red[4] + red[5] + red[6] + red[7];
  const float mu = s * (1.f / 768.f);
  const float var = ss * (1.f / 768.f) - mu * mu;
  const float rs = rsqrtf(var + 1e-5f);
  unsigned short* orow = out + (size_t)row * 768;
  orow[tid]       = f2b((v0 - mu) * rs * w[tid]       + bse[tid]);
  orow[tid + 256] = f2b((v1 - mu) * rs * w[tid + 256] + bse[tid + 256]);
  orow[tid + 512] = f2b((v2 - mu) * rs * w[tid + 512] + bse[tid + 512]);
}

// ---------------------------------------------------------------------------
// Persistent 8-phase GEMM (m201 template, persistent-block variant).
//   grid = 256 (1 block/CU, LDS-forced). Each block owns a contiguous
//   bm-major run of 256x256 output tiles (XCD-contiguous assignment via
//   p = (bid&7)*32 + bid>>3) -> A-panel L2 reuse across its tiles.
//   Overlap: next tile's A staged into sAB[0..1] BEFORE the epilogue
//   (eps lives in sAB[2..3] only, 8 passes x 32 rows, ESTR=260 = 33 KB);
//   B staged after last eps read; gate vmcnt(4) before next K-loop
//   (queue: [A:8][stores][B:8] -> vmcnt(4) lands A+stores+B(t0)).
//   In-loop depth-2 staging + vmcnt(8) invariant unchanged.
// EPI 0: bf16 out.  EPI 1: fp32 out + residual.  EPI 2: bf16 out + GELU.
// ---------------------------------------------------------------------------
#define STG_A(t2, dstbase, GRPE) { \
    const int kt2_ = (t2) * 64; \
    _Pragma("unroll") for (int j = 0; j < 2; ++j) { \
      const int idx = wid * 2 + j; \
      const int grp = (GRPE); \
      int grow = bm * 256 + grp * 8 + srow; if (grow >= M) grow = M - 1; \
      GLOAD_LDS16(A + (size_t)grow * K + kt2_ + scol, (dstbase) + grp * 512); \
    } }
#define STG_B(t2, dstbase, GRPE) { \
    const int kt2_ = (t2) * 64; \
    _Pragma("unroll") for (int j = 0; j < 2; ++j) { \
      const int idx = wid * 2 + j; \
      const int grp = (GRPE); \
      const int grow = bn * 256 + grp * 8 + srow; \
      GLOAD_LDS16(Bt + (size_t)grow * K + kt2_ + scol, (dstbase) + grp * 512); \
    } }
#define GRP_A0 (idx + (idx & 8))
#define GRP_A1 (idx + (idx & 8) + 8)
#define GRP_B0 (((idx >> 2) << 3) + (idx & 3))
#define GRP_B1 (((idx >> 2) << 3) + 4 + (idx & 3))
#define LGKM0 asm volatile("s_waitcnt lgkmcnt(0)" ::: "memory"); __builtin_amdgcn_sched_barrier(0)

template<int EPI>
__global__ __launch_bounds__(512, 2) void gemm8p(
    const unsigned short* __restrict__ A, const unsigned short* __restrict__ Bt,
    const float* __restrict__ bias, const float* __restrict__ res,
    unsigned short* __restrict__ obf, float* __restrict__ of32,
    int M, int N, int K)
{
  __shared__ __align__(16) unsigned short sAB[4][256 * 64];  // sA=0,1  sB=2,3
  const int tid = threadIdx.x;
  const int wid = tid >> 6, ln = tid & 63;
  const int wr = wid >> 2, wc = wid & 3;
  const int l15 = ln & 15, lg = ln >> 4;
  const int l7 = l15 & 7;
  const int uo0 = ((lg) ^ l7) * 8;        // swizzled byte-slot, kk=0
  const int uo1 = ((4 + lg) ^ l7) * 8;    // kk=1
  const int srow = ln >> 3;
  const int scol = ((ln & 7) ^ srow) * 8; // inverse-swizzled global col
  const int NT = K >> 6;

  const int gx = N >> 8;
  const int tiles = ((M + 255) >> 8) * gx;
  // persistent assignment, XCD-contiguous: each XCD gets a contiguous
  // run of bm-major tile space -> few A panels per XCD L2.
  const int p = (blockIdx.x & 7) * 32 + (blockIdx.x >> 3);
  const int q = tiles >> 8, r = tiles & 255;
  int tt = p * q + (p < r ? p : r);
  const int tend = tt + q + (p < r ? 1 : 0);
  if (tt >= tend) return;

  int bm = tt / gx, bn = tt - bm * gx;

  const int arow = wr * 128 + l15;
  const int brow = wc * 64 + l15;

  sh8 afr[4][2], b0r[2][2], b1r[2][2];

  // prologue for the first tile: A(t0),A(t1) then B(t0),B(t1); gate vmcnt(4)
  STG_A(0, sAB[0], GRP_A0); STG_A(0, sAB[0], GRP_A1);
  STG_A(1, sAB[1], GRP_A0); STG_A(1, sAB[1], GRP_A1);
  STG_B(0, sAB[2], GRP_B0); STG_B(0, sAB[2], GRP_B1);
  STG_B(1, sAB[3], GRP_B0); STG_B(1, sAB[3], GRP_B1);
  asm volatile("s_waitcnt vmcnt(4)" ::: "memory");
  __builtin_amdgcn_s_barrier();

  while (true) {
    f32x4 acc[8][4] = {};

    for (int t = 0; t < NT; ++t) {
      unsigned short* sAp = sAB[t & 1];
      unsigned short* sBp = sAB[2 + (t & 1)];
      const bool pre = (t + 2 < NT);

      // ---- P1 (Q00): read A-half0 + B-half0 + B-half1 (b1r hoisted) ----
#pragma unroll
      for (int mi = 0; mi < 4; ++mi) {
        afr[mi][0] = *(const sh8*)(sAp + (arow + mi * 16) * 64 + uo0);
        afr[mi][1] = *(const sh8*)(sAp + (arow + mi * 16) * 64 + uo1);
      }
#pragma unroll
      for (int ni = 0; ni < 2; ++ni) {
        b0r[ni][0] = *(const sh8*)(sBp + (brow + ni * 16) * 64 + uo0);
        b0r[ni][1] = *(const sh8*)(sBp + (brow + ni * 16) * 64 + uo1);
        b1r[ni][0] = *(const sh8*)(sBp + (brow + (ni + 2) * 16) * 64 + uo0);
        b1r[ni][1] = *(const sh8*)(sBp + (brow + (ni + 2) * 16) * 64 + uo1);
      }
      __builtin_amdgcn_s_barrier();
      LGKM0;
      __builtin_amdgcn_s_setprio(1);
#pragma unroll
      for (int kk = 0; kk < 2; ++kk)
#pragma unroll
        for (int mi = 0; mi < 4; ++mi)
#pragma unroll
          for (int ni = 0; ni < 2; ++ni)
            acc[mi][ni] = __builtin_amdgcn_mfma_f32_16x16x32_bf16(afr[mi][kk], b0r[ni][kk], acc[mi][ni], 0, 0, 0);
      __builtin_amdgcn_s_setprio(0);
      __builtin_amdgcn_sched_barrier(0);
      __builtin_amdgcn_s_barrier();

      // ---- P2 (Q01): stage A-half0 of t+2 ----
      if (pre) STG_A(t + 2, sAp, GRP_A0);
      __builtin_amdgcn_s_barrier();
      LGKM0;
      __builtin_amdgcn_s_setprio(1);
#pragma unroll
      for (int kk = 0; kk < 2; ++kk)
#pragma unroll
        for (int mi = 0; mi < 4; ++mi)
#pragma unroll
          for (int ni = 0; ni < 2; ++ni)
            acc[mi][ni + 2] = __builtin_amdgcn_mfma_f32_16x16x32_bf16(afr[mi][kk], b1r[ni][kk], acc[mi][ni + 2], 0, 0, 0);
      __builtin_amdgcn_s_setprio(0);
      __builtin_amdgcn_sched_barrier(0);
      __builtin_amdgcn_s_barrier();

      // ---- P3 (Q11): read A-half1; stage B of t+2 ----
#pragma unroll
      for (int mi = 0; mi < 4; ++mi) {
        afr[mi][0] = *(const sh8*)(sAp + (arow + (mi + 4) * 16) * 64 + uo0);
        afr[mi][1] = *(const sh8*)(sAp + (arow + (mi + 4) * 16) * 64 + uo1);
      }
      if (pre) { STG_B(t + 2, sBp, GRP_B0); STG_B(t + 2, sBp, GRP_B1); }
      __builtin_amdgcn_s_barrier();
      LGKM0;
      __builtin_amdgcn_s_setprio(1);
#pragma unroll
      for (int kk = 0; kk < 2; ++kk)
#pragma unroll
        for (int mi = 0; mi < 4; ++mi)
#pragma unroll
          for (int ni = 0; ni < 2; ++ni)
            acc[mi + 4][ni + 2] = __builtin_amdgcn_mfma_f32_16x16x32_bf16(afr[mi][kk], b1r[ni][kk], acc[mi + 4][ni + 2], 0, 0, 0);
      __builtin_amdgcn_s_setprio(0);
      __builtin_amdgcn_sched_barrier(0);
      __builtin_amdgcn_s_barrier();

      // ---- P4 (Q10): stage A-half1 of t+2; counted vmcnt at tile end ----
      if (pre) STG_A(t + 2, sAp, GRP_A1);
      __builtin_amdgcn_s_barrier();
      __builtin_amdgcn_s_setprio(1);
#pragma unroll
      for (int kk = 0; kk < 2; ++kk)
#pragma unroll
        for (int mi = 0; mi < 4; ++mi)
#pragma unroll
          for (int ni = 0; ni < 2; ++ni)
            acc[mi + 4][ni] = __builtin_amdgcn_mfma_f32_16x16x32_bf16(afr[mi][kk], b0r[ni][kk], acc[mi + 4][ni], 0, 0, 0);
      __builtin_amdgcn_s_setprio(0);
      __builtin_amdgcn_sched_barrier(0);
      if (t + 1 < NT) {
        if (pre) { asm volatile("s_waitcnt vmcnt(8)" ::: "memory"); }
        else     { asm volatile("s_waitcnt vmcnt(0)" ::: "memory"); }
        __builtin_amdgcn_s_barrier();
      }
    }

    const int obm = bm, obn = bn;
    const bool more = (tt + 1 < tend);
    if (more) { ++tt; bm = tt / gx; bn = tt - bm * gx; }

    // All waves must exit the K-loop (done reading sAB[0..1]) before
    // next tile's A staging overwrites them.
    __builtin_amdgcn_s_barrier();
    if (more) {
      STG_A(0, sAB[0], GRP_A0); STG_A(0, sAB[0], GRP_A1);
      STG_A(1, sAB[1], GRP_A0); STG_A(1, sAB[1], GRP_A1);
    }

    // ---- epilogue: eps confined to sAB[2..3]; 8 passes of 32 rows ----
    constexpr int ESTR = 260;             // f32 stride: 16B-aligned, 2-way alias
    float* eps = (float*)(sAB[2]);        // 32*260*4 = 33,280 B <= 65,536
#pragma unroll
    for (int pass = 0; pass < 8; ++pass) {
      __builtin_amdgcn_s_barrier();
      if (wr == (pass >> 2)) {
        const int mib = (pass & 3) * 2;
#pragma unroll
        for (int mi = 0; mi < 2; ++mi)
#pragma unroll
          for (int ni = 0; ni < 4; ++ni)
#pragma unroll
            for (int rr = 0; rr < 4; ++rr)
              eps[(mi * 16 + lg * 4 + rr) * ESTR + wc * 64 + ni * 16 + l15] = acc[mib + mi][ni][rr];
      }
      __builtin_amdgcn_s_barrier();
#pragma unroll
      for (int pp = 0; pp < 4; ++pp) {
        const int idx = pp * 512 + tid;   // 0..2047
        const int rl = idx >> 6;          // 0..31
        const int c4 = (idx & 63) * 4;    // col in tile
        const int grow = obm * 256 + pass * 32 + rl;
        if (grow < M) {
          f32x4 v = *(const f32x4*)(eps + rl * ESTR + c4);
          const int gcol = obn * 256 + c4;
          const f32x4 bv = *(const f32x4*)(bias + gcol);
          v += bv;
          if (EPI == 2) {
#pragma unroll
            for (int e = 0; e < 4; ++e) v[e] = fast_gelu(v[e]);
          }
          if (EPI == 1) {
            const f32x4 rv = *(const f32x4*)(res + (size_t)grow * N + gcol);
            v += rv;
            *(f32x4*)(of32 + (size_t)grow * N + gcol) = v;
          } else {
            us4 o = { f2b(v[0]), f2b(v[1]), f2b(v[2]), f2b(v[3]) };
            *(us4*)(obf + (size_t)grow * N + gcol) = o;
          }
        }
      }
    }

    if (!more) break;

    // All waves done reading eps (sAB[2..3]) before B staging overwrites.
    __builtin_amdgcn_s_barrier();
    STG_B(0, sAB[2], GRP_B0); STG_B(0, sAB[2], GRP_B1);
    STG_B(1, sAB[3], GRP_B0); STG_B(1, sAB[3], GRP_B1);
    // queue: [A:8][epilogue stores][B:8] -> vmcnt(4) guarantees A, stores,
    // and B(t0) landed; B(t1) may fly (consumed at t=1, gated by vmcnt(8)).
    asm volatile("s_waitcnt vmcnt(4)" ::: "memory");
    __builtin_amdgcn_s_barrier();
  }
}

// ---------------------------------------------------------------------------
// Flash attention (unchanged).
// ---------------------------------------------------------------------------
__global__ __launch_bounds__(256) void attn(
    const unsigned short* __restrict__ qkv, unsigned short* __restrict__ ctx)
{
  constexpr int KP = 72;
  __shared__ __align__(16) unsigned short sQ[64 * KP];
  __shared__ __align__(16) unsigned short sK[64 * KP];
  __shared__ __align__(16) unsigned short sVT[64 * KP];
  __shared__ __align__(16) unsigned short sP[4][16 * KP];
  const int tid = threadIdx.x, wv = tid >> 6, ln = tid & 63;
  const int l15 = ln & 15, lg = ln >> 4;
  const int b = blockIdx.z, h = blockIdx.y, qt = blockIdx.x;
  const size_t base = (size_t)b * S_ * 2304 + h * 64;
  const unsigned short* qp = qkv + base;
  const unsigned short* kp = qkv + base + 768;
  const unsigned short* vp = qkv + base + 1536;

  {
    const int r = tid >> 2, c = (tid & 3) * 16;
    int row = qt * 64 + r; if (row >= S_) row = S_ - 1;
    const unsigned short* g = qp + (size_t)row * 2304 + c;
#pragma unroll
    for (int half = 0; half < 2; ++half) {
      sh8 v = *(const sh8*)(g + half * 8);
      unsigned short o[8];
#pragma unroll
      for (int j = 0; j < 8; ++j) o[j] = f2b(b2f((unsigned short)v[j]) * 0.125f);
      *(sh8*)(sQ + r * KP + c + half * 8) = *(sh8*)o;
    }
  }

  f32x4 oacc[4] = {};
  float m_run = -1e30f, l_run = 0.f;
  const int nt = (S_ + 63) / 64;
  for (int t = 0; t < nt; ++t) {
    __syncthreads();
    {
      const int r = tid >> 2, c = (tid & 3) * 16;
      int row = t * 64 + r; if (row >= S_) row = S_ - 1;
      const unsigned short* g = kp + (size_t)row * 2304 + c;
      *(sh8*)(sK + r * KP + c)     = *(const sh8*)g;
      *(sh8*)(sK + r * KP + c + 8) = *(const sh8*)(g + 8);
    }
#pragma unroll
    for (int uu = 0; uu < 2; ++uu) {
      const int u = tid + uu * 256;
      const int e = u & 63, kvb = u >> 6;
      unsigned short val[8];
#pragma unroll
      for (int j = 0; j < 8; ++j) {
        int row = t * 64 + kvb * 8 + j; if (row >= S_) row = S_ - 1;
        val[j] = vp[(size_t)row * 2304 + e];
      }
      *(sh8*)(sVT + e * KP + kvb * 8) = *(sh8*)val;
    }
    __syncthreads();

    f32x4 sacc[4] = {};
#pragma unroll
    for (int kk = 0; kk < 2; ++kk) {
      sh8 bq = *(const sh8*)(sQ + (wv * 16 + l15) * KP + kk * 32 + lg * 8);
#pragma unroll
      for (int f = 0; f < 4; ++f) {
        sh8 ak = *(const sh8*)(sK + (f * 16 + l15) * KP + kk * 32 + lg * 8);
        sacc[f] = __builtin_amdgcn_mfma_f32_16x16x32_bf16(ak, bq, sacc[f], 0, 0, 0);
      }
    }

    float sv[4][4];
    float pmax = -1e30f;
#pragma unroll
    for (int f = 0; f < 4; ++f)
#pragma unroll
      for (int r = 0; r < 4; ++r) {
        const int kva = t * 64 + f * 16 + lg * 4 + r;
        float sc = sacc[f][r];
        if (kva >= S_) sc = -1e30f;
        sv[f][r] = sc;
        pmax = fmaxf(pmax, sc);
      }
    pmax = fmaxf(pmax, __shfl_xor(pmax, 16));
    pmax = fmaxf(pmax, __shfl_xor(pmax, 32));
    const float mnew = fmaxf(m_run, pmax);
    const float alpha = __expf(m_run - mnew);
    float psum = 0.f;
    unsigned short pb[4][4];
#pragma unroll
    for (int f = 0; f < 4; ++f)
#pragma unroll
      for (int r = 0; r < 4; ++r) {
        const float p = __expf(sv[f][r] - mnew);
        psum += p;
        pb[f][r] = f2b(p);
      }
    psum += __shfl_xor(psum, 16);
    psum += __shfl_xor(psum, 32);
    l_run = l_run * alpha + psum;
    m_run = mnew;
#pragma unroll
    for (int f = 0; f < 4; ++f) {
      oacc[f][0] *= alpha; oacc[f][1] *= alpha;
      oacc[f][2] *= alpha; oacc[f][3] *= alpha;
    }
#pragma unroll
    for (int f = 0; f < 4; ++f) {
      us4 pk = { pb[f][0], pb[f][1], pb[f][2], pb[f][3] };
      *(us4*)(sP[wv] + l15 * KP + f * 16 + lg * 4) = pk;
    }
    __syncthreads();

#pragma unroll
    for (int kk = 0; kk < 2; ++kk) {
      sh8 bp = *(const sh8*)(sP[wv] + l15 * KP + kk * 32 + lg * 8);
#pragma unroll
      for (int fe = 0; fe < 4; ++fe) {
        sh8 av = *(const sh8*)(sVT + (fe * 16 + l15) * KP + kk * 32 + lg * 8);
        oacc[fe] = __builtin_amdgcn_mfma_f32_16x16x32_bf16(av, bp, oacc[fe], 0, 0, 0);
      }
    }
  }

  const int qa = qt * 64 + wv * 16 + l15;
  if (qa < S_) {
    const float inv = 1.f / l_run;
    const size_t orow = ((size_t)b * S_ + qa) * 768 + h * 64;
#pragma unroll
    for (int fe = 0; fe < 4; ++fe) {
      unsigned short pk[4];
#pragma unroll
      for (int r = 0; r < 4; ++r) pk[r] = f2b(oacc[fe][r] * inv);
      *(us4*)(ctx + orow + fe * 16 + lg * 4) = *(us4*)pk;
    }
  }
}

// ---------------------------------------------------------------------------
extern "C" void kernel_launch(void* const* d_in, const int* in_sizes, int n_in,
                              void* d_out, int out_size, void* d_ws, size_t ws_size,
                              hipStream_t stream)
{
  const float* x    = (const float*)d_in[0];
  const float* ln1w = (const float*)d_in[1];
  const float* ln1b = (const float*)d_in[2];
  const float* Wq   = (const float*)d_in[3];
  const float* bq   = (const float*)d_in[4];
  const float* Wk   = (const float*)d_in[5];
  const float* bk   = (const float*)d_in[6];
  const float* Wv   = (const float*)d_in[7];
  const float* bv   = (const float*)d_in[8];
  const float* Wo   = (const float*)d_in[9];
  const float* bo   = (const float*)d_in[10];
  const float* ln2w = (const float*)d_in[11];
  const float* ln2b = (const float*)d_in[12];
  const float* W1   = (const float*)d_in[13];
  const float* b1   = (const float*)d_in[14];
  const float* W2   = (const float*)d_in[15];
  const float* b2   = (const float*)d_in[16];
  float* out = (float*)d_out;
  char* ws = (char*)d_ws;

  unsigned short* wqkvT = (unsigned short*)(ws + 0);          //  3,538,944
  unsigned short* woT   = (unsigned short*)(ws + 3538944);    //  1,179,648
  unsigned short* w1T   = (unsigned short*)(ws + 4718592);    //  4,718,592
  unsigned short* w2T   = (unsigned short*)(ws + 9437184);    //  4,718,592
  float*          biasq = (float*)(ws + 14155776);            //      9,216
  unsigned short* hbf   = (unsigned short*)(ws + 14164992);   // 28,360,704
  unsigned short* qkvb  = (unsigned short*)(ws + 42525696);   // 85,082,112
  unsigned short* ctxb  = (unsigned short*)(ws + 127607808);  // 28,360,704
  unsigned short* mlp1  = qkvb;   // overlays dead qkv+ctx

  packQKV64<<<dim3(12, 12, 3), 256, 0, stream>>>(Wq, Wk, Wv, wqkvT);
  bias_pack<<<9, 256, 0, stream>>>(bq, bk, bv, biasq);
  packT64<<<dim3(12, 12), 256, 0, stream>>>(Wo, woT, 768, 768);
  packT64<<<dim3(48, 12), 256, 0, stream>>>(W1, w1T, 768, 3072);
  packT64<<<dim3(12, 48), 256, 0, stream>>>(W2, w2T, 3072, 768);

  ln_bf16<<<MROWS, 256, 0, stream>>>(x, ln1w, ln1b, hbf);
  gemm8p<0><<<256, 512, 0, stream>>>(hbf, wqkvT, biasq, nullptr, qkvb, nullptr,
                                     MROWS, 2304, 768);
  attn<<<dim3(10, 12, 32), 256, 0, stream>>>(qkvb, ctxb);
  gemm8p<1><<<256, 512, 0, stream>>>(ctxb, woT, bo, x, nullptr, out,
                                     MROWS, 768, 768);
  ln_bf16<<<MROWS, 256, 0, stream>>>(out, ln2w, ln2b, hbf);
  gemm8p<2><<<256, 512, 0, stream>>>(hbf, w1T, b1, nullptr, mlp1, nullptr,
                                     MROWS, 3072, 768);
  gemm8p<1><<<256, 512, 0, stream>>>(mlp1, w2T, b2, out, nullptr, out,
                                     MROWS, 768, 3072);
}

// Round 3
// 493.815 us; speedup vs baseline: 1.0771x; 1.0771x over previous
//
#include <hip/hip_runtime.h>
#include <hip/hip_bf16.h>
#include <stdint.h>

#define B_ 32
#define S_ 577
#define D_ 768
#define H_ 12
#define FF_ 3072
#define MROWS (B_*S_)   // 18464

typedef __attribute__((ext_vector_type(8))) short sh8;
typedef __attribute__((ext_vector_type(4))) float f32x4;
typedef __attribute__((ext_vector_type(4))) unsigned short us4;

static __device__ __forceinline__ unsigned short f2b(float f) {
  __hip_bfloat16 h = __float2bfloat16(f);
  return *reinterpret_cast<unsigned short*>(&h);
}
static __device__ __forceinline__ float b2f(unsigned short u) {
  __hip_bfloat16 h;
  *reinterpret_cast<unsigned short*>(&h) = u;
  return __bfloat162float(h);
}

// Branch-free exact-GELU: 0.5*v*(1+erf(v/sqrt2)) with erf via A&S 7.1.26.
// |err(erf)| <= 1.5e-7 -> ~1e-7 output err, 5 orders below bf16 rounding.
static __device__ __forceinline__ float fast_gelu(float v) {
  const float z = fabsf(v) * 0.70710678118f;
  const float t = __builtin_amdgcn_rcpf(__builtin_fmaf(0.3275911f, z, 1.0f));
  float p = 1.061405429f;
  p = __builtin_fmaf(p, t, -1.453152027f);
  p = __builtin_fmaf(p, t,  1.421413741f);
  p = __builtin_fmaf(p, t, -0.284496736f);
  p = __builtin_fmaf(p, t,  0.254829592f);
  p = p * t;
  const float e = __expf(-z * z);
  const float erf_abs = __builtin_fmaf(-p, e, 1.0f);   // erf(|x|)
  const float erf_v = copysignf(erf_abs, v);
  const float hv = 0.5f * v;
  return __builtin_fmaf(hv, erf_v, hv);                // 0.5v*(1+erf)
}

#define GLOAD_LDS16(gp, lp) \
  __builtin_amdgcn_global_load_lds((const __attribute__((address_space(1))) unsigned int*)(gp), \
                                   (__attribute__((address_space(3))) unsigned int*)(lp), 16, 0, 0)

// ---------------------------------------------------------------------------
// Coalesced transpose-packs: fp32 [K][N] -> bf16 [N][K] via 64x64 LDS tiles
// ---------------------------------------------------------------------------
__global__ __launch_bounds__(256) void packT64(
    const float* __restrict__ src, unsigned short* __restrict__ dst, int K, int N)
{
  __shared__ unsigned short t[64][65];
  const int tid = threadIdx.x;
  const int c = tid & 63, r4 = tid >> 6;
  const int kb = blockIdx.y * 64, nb = blockIdx.x * 64;
#pragma unroll
  for (int p = 0; p < 16; ++p) {
    const int ko = p * 4 + r4;
    t[c][ko] = f2b(src[(size_t)(kb + ko) * N + nb + c]);
  }
  __syncthreads();
#pragma unroll
  for (int p = 0; p < 16; ++p) {
    const int rr = p * 4 + r4;
    dst[(size_t)(nb + rr) * K + kb + c] = t[rr][c];
  }
}

// per-head transpose for Wq/Wk/Wv [H][768][64] -> wT[(which*768+h*64+e)][768]
__global__ __launch_bounds__(256) void packQKV64(
    const float* __restrict__ Wq, const float* __restrict__ Wk, const float* __restrict__ Wv,
    unsigned short* __restrict__ dst)
{
  __shared__ unsigned short t[64][65];
  const int tid = threadIdx.x;
  const int c = tid & 63, r4 = tid >> 6;
  const int kb = blockIdx.x * 64;         // d tile (12)
  const int h = blockIdx.y;               // head (12)
  const int which = blockIdx.z;           // 0:q 1:k 2:v
  const float* src = ((which == 0) ? Wq : (which == 1) ? Wk : Wv) + (size_t)h * 768 * 64;
#pragma unroll
  for (int p = 0; p < 16; ++p) {
    const int ko = p * 4 + r4;
    t[c][ko] = f2b(src[(size_t)(kb + ko) * 64 + c]);
  }
  __syncthreads();
  unsigned short* db = dst + (size_t)(which * 768 + h * 64) * 768;
#pragma unroll
  for (int p = 0; p < 16; ++p) {
    const int rr = p * 4 + r4;            // e
    db[(size_t)rr * 768 + kb + c] = t[rr][c];
  }
}

__global__ __launch_bounds__(256) void bias_pack(
    const float* __restrict__ bq, const float* __restrict__ bk, const float* __restrict__ bv,
    float* __restrict__ biasq)
{
  const int idx = blockIdx.x * 256 + threadIdx.x;
  if (idx < 2304) {
    const int wb = idx / 768, rb = idx - wb * 768;
    const float* bb = (wb == 0) ? bq : (wb == 1) ? bk : bv;
    biasq[idx] = bb[rb];
  }
}

// ---------------------------------------------------------------------------
// LayerNorm fp32 -> bf16 (one 256-thread block per row of 768)
// ---------------------------------------------------------------------------
__global__ __launch_bounds__(256) void ln_bf16(
    const float* __restrict__ x, const float* __restrict__ w, const float* __restrict__ bse,
    unsigned short* __restrict__ out)
{
  const int row = blockIdx.x;
  const int tid = threadIdx.x;
  const float* xr = x + (size_t)row * 768;
  float v0 = xr[tid], v1 = xr[tid + 256], v2 = xr[tid + 512];
  float s = v0 + v1 + v2;
  float ss = v0 * v0 + v1 * v1 + v2 * v2;
#pragma unroll
  for (int off = 32; off >= 1; off >>= 1) {
    s  += __shfl_xor(s, off);
    ss += __shfl_xor(ss, off);
  }
  __shared__ float red[8];
  const int wv = tid >> 6, ln = tid & 63;
  if (ln == 0) { red[wv] = s; red[wv + 4] = ss; }
  __syncthreads();
  s  = red[0] + red[1] + red[2] + red[3];
  ss = red[4] + red[5] + red[6] + red[7];
  const float mu = s * (1.f / 768.f);
  const float var = ss * (1.f / 768.f) - mu * mu;
  const float rs = rsqrtf(var + 1e-5f);
  unsigned short* orow = out + (size_t)row * 768;
  orow[tid]       = f2b((v0 - mu) * rs * w[tid]       + bse[tid]);
  orow[tid + 256] = f2b((v1 - mu) * rs * w[tid + 256] + bse[tid + 256]);
  orow[tid + 512] = f2b((v2 - mu) * rs * w[tid + 512] + bse[tid + 512]);
}

// ---------------------------------------------------------------------------
// m97-style occupancy-first GEMM: 128x128 tile, BK=64, 256 thr = 4 waves
// (2M x 2N, per-wave 64x64 out). Single-buffered 32 KiB LDS -> ~3 blocks/CU;
// TLP hides the stage->vmcnt(0)->barrier drain (m114: implicit wave overlap
// ~= explicit pipelining). Keeps: T2 swizzle via pre-swizzled global source
// (linear LDS dest for global_load_lds), width-16 global_load_lds, bijective
// XCD-chunked tile assignment (contiguous bm-major run per XCD -> A/B L2
// locality), LDS-staged coalesced epilogue (4 passes x 32 rows, ESTR=132).
// EPI 0: bf16 out.  EPI 1: fp32 out + residual.  EPI 2: bf16 out + GELU.
// ---------------------------------------------------------------------------
template<int EPI>
__global__ __launch_bounds__(256, 3) void gemm128(
    const unsigned short* __restrict__ A, const unsigned short* __restrict__ Bt,
    const float* __restrict__ bias, const float* __restrict__ res,
    unsigned short* __restrict__ obf, float* __restrict__ of32,
    int M, int N, int K)
{
  __shared__ __align__(16) unsigned short sAB[2][128 * 64];  // A, B: 16 KiB each
  const int tid = threadIdx.x;
  const int wid = tid >> 6, ln = tid & 63;
  const int wr = wid >> 1, wc = wid & 1;
  const int l15 = ln & 15, lg = ln >> 4;
  const int l7 = l15 & 7;
  const int uo0 = ((lg) ^ l7) * 8;        // swizzled short-offset, kk=0
  const int uo1 = ((4 + lg) ^ l7) * 8;    // kk=1
  const int srow = ln >> 3;               // 0..7
  const int scol = ((ln & 7) ^ srow) * 8; // inverse-swizzled global col
  const int NT = K >> 6;

  // bijective XCD-chunked tile assignment (m204)
  const int gx = N >> 7;
  const int nwg = gridDim.x;
  const int q = nwg >> 3, r = nwg & 7;
  const int x = blockIdx.x & 7, ii = blockIdx.x >> 3;
  const int wg = (x < r ? x * (q + 1) : r * (q + 1) + (x - r) * q) + ii;
  const int bm = wg / gx, bn = wg - bm * gx;

  const int arow = wr * 64 + l15;
  const int brow = wc * 64 + l15;

  f32x4 acc[4][4] = {};

  for (int t = 0; t < NT; ++t) {
    const int kt = t * 64;
    __syncthreads();   // all waves done reading previous tile
#pragma unroll
    for (int j = 0; j < 4; ++j) {
      const int idx = wid * 4 + j;
      int ga = bm * 128 + idx * 8 + srow; if (ga >= M) ga = M - 1;
      GLOAD_LDS16(A + (size_t)ga * K + kt + scol, sAB[0] + idx * 512);
    }
#pragma unroll
    for (int j = 0; j < 4; ++j) {
      const int idx = wid * 4 + j;
      const int gb = bn * 128 + idx * 8 + srow;
      GLOAD_LDS16(Bt + (size_t)gb * K + kt + scol, sAB[1] + idx * 512);
    }
    asm volatile("s_waitcnt vmcnt(0)" ::: "memory");
    __syncthreads();

#pragma unroll
    for (int kk = 0; kk < 2; ++kk) {
      const int uo = kk ? uo1 : uo0;
      sh8 af[4], bf[4];
#pragma unroll
      for (int mi = 0; mi < 4; ++mi)
        af[mi] = *(const sh8*)(sAB[0] + (arow + mi * 16) * 64 + uo);
#pragma unroll
      for (int ni = 0; ni < 4; ++ni)
        bf[ni] = *(const sh8*)(sAB[1] + (brow + ni * 16) * 64 + uo);
#pragma unroll
      for (int mi = 0; mi < 4; ++mi)
#pragma unroll
        for (int ni = 0; ni < 4; ++ni)
          acc[mi][ni] = __builtin_amdgcn_mfma_f32_16x16x32_bf16(af[mi], bf[ni], acc[mi][ni], 0, 0, 0);
    }
  }

  // ---- LDS-staged coalesced epilogue: 4 passes of 32 rows ----
  constexpr int ESTR = 132;               // f32 stride: 16B-aligned, bank-spread
  float* eps = (float*)sAB;               // 32*132*4 = 16,896 B <= 32,768
#pragma unroll
  for (int pass = 0; pass < 4; ++pass) {
    __syncthreads();
    if (wr == (pass >> 1)) {
      const int mib = (pass & 1) * 2;
#pragma unroll
      for (int ml = 0; ml < 2; ++ml)
#pragma unroll
        for (int ni = 0; ni < 4; ++ni)
#pragma unroll
          for (int rr = 0; rr < 4; ++rr)
            eps[(ml * 16 + lg * 4 + rr) * ESTR + wc * 64 + ni * 16 + l15] = acc[mib + ml][ni][rr];
    }
    __syncthreads();
#pragma unroll
    for (int pp = 0; pp < 4; ++pp) {
      const int idx = pp * 256 + tid;     // 0..1023
      const int rl = idx >> 5;            // 0..31
      const int c4 = (idx & 31) * 4;      // col in tile
      const int grow = bm * 128 + pass * 32 + rl;
      if (grow < M) {
        f32x4 v = *(const f32x4*)(eps + rl * ESTR + c4);
        const int gcol = bn * 128 + c4;
        const f32x4 bv = *(const f32x4*)(bias + gcol);
        v += bv;
        if (EPI == 2) {
#pragma unroll
          for (int e = 0; e < 4; ++e) v[e] = fast_gelu(v[e]);
        }
        if (EPI == 1) {
          const f32x4 rv = *(const f32x4*)(res + (size_t)grow * N + gcol);
          v += rv;
          *(f32x4*)(of32 + (size_t)grow * N + gcol) = v;
        } else {
          us4 o = { f2b(v[0]), f2b(v[1]), f2b(v[2]), f2b(v[3]) };
          *(us4*)(obf + (size_t)grow * N + gcol) = o;
        }
      }
    }
  }
}

// ---------------------------------------------------------------------------
// Flash attention (unchanged).
// ---------------------------------------------------------------------------
__global__ __launch_bounds__(256) void attn(
    const unsigned short* __restrict__ qkv, unsigned short* __restrict__ ctx)
{
  constexpr int KP = 72;
  __shared__ __align__(16) unsigned short sQ[64 * KP];
  __shared__ __align__(16) unsigned short sK[64 * KP];
  __shared__ __align__(16) unsigned short sVT[64 * KP];
  __shared__ __align__(16) unsigned short sP[4][16 * KP];
  const int tid = threadIdx.x, wv = tid >> 6, ln = tid & 63;
  const int l15 = ln & 15, lg = ln >> 4;
  const int b = blockIdx.z, h = blockIdx.y, qt = blockIdx.x;
  const size_t base = (size_t)b * S_ * 2304 + h * 64;
  const unsigned short* qp = qkv + base;
  const unsigned short* kp = qkv + base + 768;
  const unsigned short* vp = qkv + base + 1536;

  {
    const int r = tid >> 2, c = (tid & 3) * 16;
    int row = qt * 64 + r; if (row >= S_) row = S_ - 1;
    const unsigned short* g = qp + (size_t)row * 2304 + c;
#pragma unroll
    for (int half = 0; half < 2; ++half) {
      sh8 v = *(const sh8*)(g + half * 8);
      unsigned short o[8];
#pragma unroll
      for (int j = 0; j < 8; ++j) o[j] = f2b(b2f((unsigned short)v[j]) * 0.125f);
      *(sh8*)(sQ + r * KP + c + half * 8) = *(sh8*)o;
    }
  }

  f32x4 oacc[4] = {};
  float m_run = -1e30f, l_run = 0.f;
  const int nt = (S_ + 63) / 64;
  for (int t = 0; t < nt; ++t) {
    __syncthreads();
    {
      const int r = tid >> 2, c = (tid & 3) * 16;
      int row = t * 64 + r; if (row >= S_) row = S_ - 1;
      const unsigned short* g = kp + (size_t)row * 2304 + c;
      *(sh8*)(sK + r * KP + c)     = *(const sh8*)g;
      *(sh8*)(sK + r * KP + c + 8) = *(const sh8*)(g + 8);
    }
#pragma unroll
    for (int uu = 0; uu < 2; ++uu) {
      const int u = tid + uu * 256;
      const int e = u & 63, kvb = u >> 6;
      unsigned short val[8];
#pragma unroll
      for (int j = 0; j < 8; ++j) {
        int row = t * 64 + kvb * 8 + j; if (row >= S_) row = S_ - 1;
        val[j] = vp[(size_t)row * 2304 + e];
      }
      *(sh8*)(sVT + e * KP + kvb * 8) = *(sh8*)val;
    }
    __syncthreads();

    f32x4 sacc[4] = {};
#pragma unroll
    for (int kk = 0; kk < 2; ++kk) {
      sh8 bq = *(const sh8*)(sQ + (wv * 16 + l15) * KP + kk * 32 + lg * 8);
#pragma unroll
      for (int f = 0; f < 4; ++f) {
        sh8 ak = *(const sh8*)(sK + (f * 16 + l15) * KP + kk * 32 + lg * 8);
        sacc[f] = __builtin_amdgcn_mfma_f32_16x16x32_bf16(ak, bq, sacc[f], 0, 0, 0);
      }
    }

    float sv[4][4];
    float pmax = -1e30f;
#pragma unroll
    for (int f = 0; f < 4; ++f)
#pragma unroll
      for (int r = 0; r < 4; ++r) {
        const int kva = t * 64 + f * 16 + lg * 4 + r;
        float sc = sacc[f][r];
        if (kva >= S_) sc = -1e30f;
        sv[f][r] = sc;
        pmax = fmaxf(pmax, sc);
      }
    pmax = fmaxf(pmax, __shfl_xor(pmax, 16));
    pmax = fmaxf(pmax, __shfl_xor(pmax, 32));
    const float mnew = fmaxf(m_run, pmax);
    const float alpha = __expf(m_run - mnew);
    float psum = 0.f;
    unsigned short pb[4][4];
#pragma unroll
    for (int f = 0; f < 4; ++f)
#pragma unroll
      for (int r = 0; r < 4; ++r) {
        const float p = __expf(sv[f][r] - mnew);
        psum += p;
        pb[f][r] = f2b(p);
      }
    psum += __shfl_xor(psum, 16);
    psum += __shfl_xor(psum, 32);
    l_run = l_run * alpha + psum;
    m_run = mnew;
#pragma unroll
    for (int f = 0; f < 4; ++f) {
      oacc[f][0] *= alpha; oacc[f][1] *= alpha;
      oacc[f][2] *= alpha; oacc[f][3] *= alpha;
    }
#pragma unroll
    for (int f = 0; f < 4; ++f) {
      us4 pk = { pb[f][0], pb[f][1], pb[f][2], pb[f][3] };
      *(us4*)(sP[wv] + l15 * KP + f * 16 + lg * 4) = pk;
    }
    __syncthreads();

#pragma unroll
    for (int kk = 0; kk < 2; ++kk) {
      sh8 bp = *(const sh8*)(sP[wv] + l15 * KP + kk * 32 + lg * 8);
#pragma unroll
      for (int fe = 0; fe < 4; ++fe) {
        sh8 av = *(const sh8*)(sVT + (fe * 16 + l15) * KP + kk * 32 + lg * 8);
        oacc[fe] = __builtin_amdgcn_mfma_f32_16x16x32_bf16(av, bp, oacc[fe], 0, 0, 0);
      }
    }
  }

  const int qa = qt * 64 + wv * 16 + l15;
  if (qa < S_) {
    const float inv = 1.f / l_run;
    const size_t orow = ((size_t)b * S_ + qa) * 768 + h * 64;
#pragma unroll
    for (int fe = 0; fe < 4; ++fe) {
      unsigned short pk[4];
#pragma unroll
      for (int r = 0; r < 4; ++r) pk[r] = f2b(oacc[fe][r] * inv);
      *(us4*)(ctx + orow + fe * 16 + lg * 4) = *(us4*)pk;
    }
  }
}

// ---------------------------------------------------------------------------
extern "C" void kernel_launch(void* const* d_in, const int* in_sizes, int n_in,
                              void* d_out, int out_size, void* d_ws, size_t ws_size,
                              hipStream_t stream)
{
  const float* x    = (const float*)d_in[0];
  const float* ln1w = (const float*)d_in[1];
  const float* ln1b = (const float*)d_in[2];
  const float* Wq   = (const float*)d_in[3];
  const float* bq   = (const float*)d_in[4];
  const float* Wk   = (const float*)d_in[5];
  const float* bk   = (const float*)d_in[6];
  const float* Wv   = (const float*)d_in[7];
  const float* bv   = (const float*)d_in[8];
  const float* Wo   = (const float*)d_in[9];
  const float* bo   = (const float*)d_in[10];
  const float* ln2w = (const float*)d_in[11];
  const float* ln2b = (const float*)d_in[12];
  const float* W1   = (const float*)d_in[13];
  const float* b1   = (const float*)d_in[14];
  const float* W2   = (const float*)d_in[15];
  const float* b2   = (const float*)d_in[16];
  float* out = (float*)d_out;
  char* ws = (char*)d_ws;

  unsigned short* wqkvT = (unsigned short*)(ws + 0);          //  3,538,944
  unsigned short* woT   = (unsigned short*)(ws + 3538944);    //  1,179,648
  unsigned short* w1T   = (unsigned short*)(ws + 4718592);    //  4,718,592
  unsigned short* w2T   = (unsigned short*)(ws + 9437184);    //  4,718,592
  float*          biasq = (float*)(ws + 14155776);            //      9,216
  unsigned short* hbf   = (unsigned short*)(ws + 14164992);   // 28,360,704
  unsigned short* qkvb  = (unsigned short*)(ws + 42525696);   // 85,082,112
  unsigned short* ctxb  = (unsigned short*)(ws + 127607808);  // 28,360,704
  unsigned short* mlp1  = qkvb;   // overlays dead qkv+ctx

  packQKV64<<<dim3(12, 12, 3), 256, 0, stream>>>(Wq, Wk, Wv, wqkvT);
  bias_pack<<<9, 256, 0, stream>>>(bq, bk, bv, biasq);
  packT64<<<dim3(12, 12), 256, 0, stream>>>(Wo, woT, 768, 768);
  packT64<<<dim3(48, 12), 256, 0, stream>>>(W1, w1T, 768, 3072);
  packT64<<<dim3(12, 48), 256, 0, stream>>>(W2, w2T, 3072, 768);

  // 145 M-tiles of 128 (M=18464)
  ln_bf16<<<MROWS, 256, 0, stream>>>(x, ln1w, ln1b, hbf);
  gemm128<0><<<145 * 18, 256, 0, stream>>>(hbf, wqkvT, biasq, nullptr, qkvb, nullptr,
                                           MROWS, 2304, 768);
  attn<<<dim3(10, 12, 32), 256, 0, stream>>>(qkvb, ctxb);
  gemm128<1><<<145 * 6, 256, 0, stream>>>(ctxb, woT, bo, x, nullptr, out,
                                          MROWS, 768, 768);
  ln_bf16<<<MROWS, 256, 0, stream>>>(out, ln2w, ln2b, hbf);
  gemm128<2><<<145 * 24, 256, 0, stream>>>(hbf, w1T, b1, nullptr, mlp1, nullptr,
                                           MROWS, 3072, 768);
  gemm128<1><<<145 * 6, 256, 0, stream>>>(mlp1, w2T, b2, out, nullptr, out,
                                          MROWS, 768, 3072);
}

// Round 4
// 484.490 us; speedup vs baseline: 1.0979x; 1.0192x over previous
//
#include <hip/hip_runtime.h>
#include <hip/hip_bf16.h>
#include <stdint.h>

#define B_ 32
#define S_ 577
#define D_ 768
#define H_ 12
#define FF_ 3072
#define MROWS (B_*S_)   // 18464

typedef __attribute__((ext_vector_type(8))) short sh8;
typedef __attribute__((ext_vector_type(4))) float f32x4;
typedef __attribute__((ext_vector_type(4))) unsigned short us4;

static __device__ __forceinline__ unsigned short f2b(float f) {
  __hip_bfloat16 h = __float2bfloat16(f);
  return *reinterpret_cast<unsigned short*>(&h);
}
static __device__ __forceinline__ float b2f(unsigned short u) {
  __hip_bfloat16 h;
  *reinterpret_cast<unsigned short*>(&h) = u;
  return __bfloat162float(h);
}

// Branch-free exact-GELU: 0.5*v*(1+erf(v/sqrt2)) with erf via A&S 7.1.26.
// |err(erf)| <= 1.5e-7 -> ~1e-7 output err, 5 orders below bf16 rounding.
static __device__ __forceinline__ float fast_gelu(float v) {
  const float z = fabsf(v) * 0.70710678118f;
  const float t = __builtin_amdgcn_rcpf(__builtin_fmaf(0.3275911f, z, 1.0f));
  float p = 1.061405429f;
  p = __builtin_fmaf(p, t, -1.453152027f);
  p = __builtin_fmaf(p, t,  1.421413741f);
  p = __builtin_fmaf(p, t, -0.284496736f);
  p = __builtin_fmaf(p, t,  0.254829592f);
  p = p * t;
  const float e = __expf(-z * z);
  const float erf_abs = __builtin_fmaf(-p, e, 1.0f);   // erf(|x|)
  const float erf_v = copysignf(erf_abs, v);
  const float hv = 0.5f * v;
  return __builtin_fmaf(hv, erf_v, hv);                // 0.5v*(1+erf)
}

#define GLOAD_LDS16(gp, lp) \
  __builtin_amdgcn_global_load_lds((const __attribute__((address_space(1))) unsigned int*)(gp), \
                                   (__attribute__((address_space(3))) unsigned int*)(lp), 16, 0, 0)

// ---------------------------------------------------------------------------
// Coalesced transpose-packs: fp32 [K][N] -> bf16 [N][K] via 64x64 LDS tiles
// ---------------------------------------------------------------------------
__global__ __launch_bounds__(256) void packT64(
    const float* __restrict__ src, unsigned short* __restrict__ dst, int K, int N)
{
  __shared__ unsigned short t[64][65];
  const int tid = threadIdx.x;
  const int c = tid & 63, r4 = tid >> 6;
  const int kb = blockIdx.y * 64, nb = blockIdx.x * 64;
#pragma unroll
  for (int p = 0; p < 16; ++p) {
    const int ko = p * 4 + r4;
    t[c][ko] = f2b(src[(size_t)(kb + ko) * N + nb + c]);
  }
  __syncthreads();
#pragma unroll
  for (int p = 0; p < 16; ++p) {
    const int rr = p * 4 + r4;
    dst[(size_t)(nb + rr) * K + kb + c] = t[rr][c];
  }
}

// per-head transpose for Wq/Wk/Wv [H][768][64] -> wT[(which*768+h*64+e)][768]
// Q weights pre-scaled by 1/8 (power of two -> bit-exact exponent shift; the
// attention 1/sqrt(Dh) scale then disappears from the attn kernel).
__global__ __launch_bounds__(256) void packQKV64(
    const float* __restrict__ Wq, const float* __restrict__ Wk, const float* __restrict__ Wv,
    unsigned short* __restrict__ dst)
{
  __shared__ unsigned short t[64][65];
  const int tid = threadIdx.x;
  const int c = tid & 63, r4 = tid >> 6;
  const int kb = blockIdx.x * 64;         // d tile (12)
  const int h = blockIdx.y;               // head (12)
  const int which = blockIdx.z;           // 0:q 1:k 2:v
  const float* src = ((which == 0) ? Wq : (which == 1) ? Wk : Wv) + (size_t)h * 768 * 64;
  const float scl = (which == 0) ? 0.125f : 1.0f;
#pragma unroll
  for (int p = 0; p < 16; ++p) {
    const int ko = p * 4 + r4;
    t[c][ko] = f2b(src[(size_t)(kb + ko) * 64 + c] * scl);
  }
  __syncthreads();
  unsigned short* db = dst + (size_t)(which * 768 + h * 64) * 768;
#pragma unroll
  for (int p = 0; p < 16; ++p) {
    const int rr = p * 4 + r4;            // e
    db[(size_t)rr * 768 + kb + c] = t[rr][c];
  }
}

__global__ __launch_bounds__(256) void bias_pack(
    const float* __restrict__ bq, const float* __restrict__ bk, const float* __restrict__ bv,
    float* __restrict__ biasq)
{
  const int idx = blockIdx.x * 256 + threadIdx.x;
  if (idx < 2304) {
    const int wb = idx / 768, rb = idx - wb * 768;
    const float* bb = (wb == 0) ? bq : (wb == 1) ? bk : bv;
    biasq[idx] = bb[rb] * (wb == 0 ? 0.125f : 1.0f);
  }
}

// ---------------------------------------------------------------------------
// LayerNorm fp32 -> bf16 (one 256-thread block per row of 768)
// ---------------------------------------------------------------------------
__global__ __launch_bounds__(256) void ln_bf16(
    const float* __restrict__ x, const float* __restrict__ w, const float* __restrict__ bse,
    unsigned short* __restrict__ out)
{
  const int row = blockIdx.x;
  const int tid = threadIdx.x;
  const float* xr = x + (size_t)row * 768;
  float v0 = xr[tid], v1 = xr[tid + 256], v2 = xr[tid + 512];
  float s = v0 + v1 + v2;
  float ss = v0 * v0 + v1 * v1 + v2 * v2;
#pragma unroll
  for (int off = 32; off >= 1; off >>= 1) {
    s  += __shfl_xor(s, off);
    ss += __shfl_xor(ss, off);
  }
  __shared__ float red[8];
  const int wv = tid >> 6, ln = tid & 63;
  if (ln == 0) { red[wv] = s; red[wv + 4] = ss; }
  __syncthreads();
  s  = red[0] + red[1] + red[2] + red[3];
  ss = red[4] + red[5] + red[6] + red[7];
  const float mu = s * (1.f / 768.f);
  const float var = ss * (1.f / 768.f) - mu * mu;
  const float rs = rsqrtf(var + 1e-5f);
  unsigned short* orow = out + (size_t)row * 768;
  orow[tid]       = f2b((v0 - mu) * rs * w[tid]       + bse[tid]);
  orow[tid + 256] = f2b((v1 - mu) * rs * w[tid + 256] + bse[tid + 256]);
  orow[tid + 512] = f2b((v2 - mu) * rs * w[tid + 512] + bse[tid + 512]);
}

// ---------------------------------------------------------------------------
// m97-style occupancy-first GEMM: 128x128 tile, BK=64, 256 thr = 4 waves.
// (unchanged from round 3 — dropped gemm out of the top-5)
// ---------------------------------------------------------------------------
template<int EPI>
__global__ __launch_bounds__(256, 3) void gemm128(
    const unsigned short* __restrict__ A, const unsigned short* __restrict__ Bt,
    const float* __restrict__ bias, const float* __restrict__ res,
    unsigned short* __restrict__ obf, float* __restrict__ of32,
    int M, int N, int K)
{
  __shared__ __align__(16) unsigned short sAB[2][128 * 64];  // A, B: 16 KiB each
  const int tid = threadIdx.x;
  const int wid = tid >> 6, ln = tid & 63;
  const int wr = wid >> 1, wc = wid & 1;
  const int l15 = ln & 15, lg = ln >> 4;
  const int l7 = l15 & 7;
  const int uo0 = ((lg) ^ l7) * 8;        // swizzled short-offset, kk=0
  const int uo1 = ((4 + lg) ^ l7) * 8;    // kk=1
  const int srow = ln >> 3;               // 0..7
  const int scol = ((ln & 7) ^ srow) * 8; // inverse-swizzled global col
  const int NT = K >> 6;

  // bijective XCD-chunked tile assignment (m204)
  const int gx = N >> 7;
  const int nwg = gridDim.x;
  const int q = nwg >> 3, r = nwg & 7;
  const int x = blockIdx.x & 7, ii = blockIdx.x >> 3;
  const int wg = (x < r ? x * (q + 1) : r * (q + 1) + (x - r) * q) + ii;
  const int bm = wg / gx, bn = wg - bm * gx;

  const int arow = wr * 64 + l15;
  const int brow = wc * 64 + l15;

  f32x4 acc[4][4] = {};

  for (int t = 0; t < NT; ++t) {
    const int kt = t * 64;
    __syncthreads();   // all waves done reading previous tile
#pragma unroll
    for (int j = 0; j < 4; ++j) {
      const int idx = wid * 4 + j;
      int ga = bm * 128 + idx * 8 + srow; if (ga >= M) ga = M - 1;
      GLOAD_LDS16(A + (size_t)ga * K + kt + scol, sAB[0] + idx * 512);
    }
#pragma unroll
    for (int j = 0; j < 4; ++j) {
      const int idx = wid * 4 + j;
      const int gb = bn * 128 + idx * 8 + srow;
      GLOAD_LDS16(Bt + (size_t)gb * K + kt + scol, sAB[1] + idx * 512);
    }
    asm volatile("s_waitcnt vmcnt(0)" ::: "memory");
    __syncthreads();

#pragma unroll
    for (int kk = 0; kk < 2; ++kk) {
      const int uo = kk ? uo1 : uo0;
      sh8 af[4], bf[4];
#pragma unroll
      for (int mi = 0; mi < 4; ++mi)
        af[mi] = *(const sh8*)(sAB[0] + (arow + mi * 16) * 64 + uo);
#pragma unroll
      for (int ni = 0; ni < 4; ++ni)
        bf[ni] = *(const sh8*)(sAB[1] + (brow + ni * 16) * 64 + uo);
#pragma unroll
      for (int mi = 0; mi < 4; ++mi)
#pragma unroll
        for (int ni = 0; ni < 4; ++ni)
          acc[mi][ni] = __builtin_amdgcn_mfma_f32_16x16x32_bf16(af[mi], bf[ni], acc[mi][ni], 0, 0, 0);
    }
  }

  // ---- LDS-staged coalesced epilogue: 4 passes of 32 rows ----
  constexpr int ESTR = 132;               // f32 stride: 16B-aligned, bank-spread
  float* eps = (float*)sAB;               // 32*132*4 = 16,896 B <= 32,768
#pragma unroll
  for (int pass = 0; pass < 4; ++pass) {
    __syncthreads();
    if (wr == (pass >> 1)) {
      const int mib = (pass & 1) * 2;
#pragma unroll
      for (int ml = 0; ml < 2; ++ml)
#pragma unroll
        for (int ni = 0; ni < 4; ++ni)
#pragma unroll
          for (int rr = 0; rr < 4; ++rr)
            eps[(ml * 16 + lg * 4 + rr) * ESTR + wc * 64 + ni * 16 + l15] = acc[mib + ml][ni][rr];
    }
    __syncthreads();
#pragma unroll
    for (int pp = 0; pp < 4; ++pp) {
      const int idx = pp * 256 + tid;     // 0..1023
      const int rl = idx >> 5;            // 0..31
      const int c4 = (idx & 31) * 4;      // col in tile
      const int grow = bm * 128 + pass * 32 + rl;
      if (grow < M) {
        f32x4 v = *(const f32x4*)(eps + rl * ESTR + c4);
        const int gcol = bn * 128 + c4;
        const f32x4 bv = *(const f32x4*)(bias + gcol);
        v += bv;
        if (EPI == 2) {
#pragma unroll
          for (int e = 0; e < 4; ++e) v[e] = fast_gelu(v[e]);
        }
        if (EPI == 1) {
          const f32x4 rv = *(const f32x4*)(res + (size_t)grow * N + gcol);
          v += rv;
          *(f32x4*)(of32 + (size_t)grow * N + gcol) = v;
        } else {
          us4 o = { f2b(v[0]), f2b(v[1]), f2b(v[2]), f2b(v[3]) };
          *(us4*)(obf + (size_t)grow * N + gcol) = o;
        }
      }
    }
  }
}

// ---------------------------------------------------------------------------
// Flash attention, VALU-thinned: QBLK=128 (8 waves, 512 thr), tail-tile
// specialization (9/10 KV tiles clamp-free), Q pre-scaled (pure-copy stage).
//   - K/V staging + fetch amortized over 2x q-rows (V gather: 8 loads/thr)
//   - per-wave structure identical to verified 4-wave version (wv now 0..7)
// LDS: sQ 128*72 + sK 64*72 + sVT 64*72 + sP 8*16*72 = 55,296 B -> 2 blk/CU.
// ---------------------------------------------------------------------------
__global__ __launch_bounds__(512) void attn(
    const unsigned short* __restrict__ qkv, unsigned short* __restrict__ ctx)
{
  constexpr int KP = 72;
  __shared__ __align__(16) unsigned short sQ[128 * KP];
  __shared__ __align__(16) unsigned short sK[64 * KP];
  __shared__ __align__(16) unsigned short sVT[64 * KP];
  __shared__ __align__(16) unsigned short sP[8][16 * KP];
  const int tid = threadIdx.x, wv = tid >> 6, ln = tid & 63;
  const int l15 = ln & 15, lg = ln >> 4;
  const int b = blockIdx.z, h = blockIdx.y, qt = blockIdx.x;
  const size_t base = (size_t)b * S_ * 2304 + h * 64;
  const unsigned short* qp = qkv + base;
  const unsigned short* kp = qkv + base + 768;
  const unsigned short* vp = qkv + base + 1536;

  // Q staging: pure copy (weights pre-scaled by 1/8 in pack)
  {
    const int r = tid >> 2, c = (tid & 3) * 16;
    int row = qt * 128 + r; if (row >= S_) row = S_ - 1;
    const unsigned short* g = qp + (size_t)row * 2304 + c;
    *(sh8*)(sQ + r * KP + c)     = *(const sh8*)g;
    *(sh8*)(sQ + r * KP + c + 8) = *(const sh8*)(g + 8);
  }

  f32x4 oacc[4] = {};
  float m_run = -1e30f, l_run = 0.f;
  const int nt = (S_ + 63) / 64;          // 10; tiles 0..8 are full
  for (int t = 0; t < nt; ++t) {
    __syncthreads();
    if (t < nt - 1) {
      // fast staging: no row clamps (t*64+63 <= 575 < 577)
      {
        const int r = tid >> 3, c = (tid & 7) * 8;
        *(sh8*)(sK + r * KP + c) = *(const sh8*)(kp + (size_t)(t * 64 + r) * 2304 + c);
      }
      {
        const int e = tid & 63, kvb = tid >> 6;
        const unsigned short* vb = vp + (size_t)(t * 64 + kvb * 8) * 2304 + e;
        unsigned short val[8];
#pragma unroll
        for (int j = 0; j < 8; ++j) val[j] = vb[(size_t)j * 2304];
        *(sh8*)(sVT + e * KP + kvb * 8) = *(sh8*)val;
      }
    } else {
      {
        const int r = tid >> 3, c = (tid & 7) * 8;
        int row = t * 64 + r; if (row >= S_) row = S_ - 1;
        *(sh8*)(sK + r * KP + c) = *(const sh8*)(kp + (size_t)row * 2304 + c);
      }
      {
        const int e = tid & 63, kvb = tid >> 6;
        unsigned short val[8];
#pragma unroll
        for (int j = 0; j < 8; ++j) {
          int row = t * 64 + kvb * 8 + j; if (row >= S_) row = S_ - 1;
          val[j] = vp[(size_t)row * 2304 + e];
        }
        *(sh8*)(sVT + e * KP + kvb * 8) = *(sh8*)val;
      }
    }
    __syncthreads();

    f32x4 sacc[4] = {};
#pragma unroll
    for (int kk = 0; kk < 2; ++kk) {
      sh8 bq = *(const sh8*)(sQ + (wv * 16 + l15) * KP + kk * 32 + lg * 8);
#pragma unroll
      for (int f = 0; f < 4; ++f) {
        sh8 ak = *(const sh8*)(sK + (f * 16 + l15) * KP + kk * 32 + lg * 8);
        sacc[f] = __builtin_amdgcn_mfma_f32_16x16x32_bf16(ak, bq, sacc[f], 0, 0, 0);
      }
    }

    if (t == nt - 1) {
#pragma unroll
      for (int f = 0; f < 4; ++f)
#pragma unroll
        for (int r = 0; r < 4; ++r)
          if (t * 64 + f * 16 + lg * 4 + r >= S_) sacc[f][r] = -1e30f;
    }
    float pmax = -1e30f;
#pragma unroll
    for (int f = 0; f < 4; ++f)
#pragma unroll
      for (int r = 0; r < 4; ++r) pmax = fmaxf(pmax, sacc[f][r]);
    pmax = fmaxf(pmax, __shfl_xor(pmax, 16));
    pmax = fmaxf(pmax, __shfl_xor(pmax, 32));
    const float mnew = fmaxf(m_run, pmax);
    const float alpha = __expf(m_run - mnew);
    float psum = 0.f;
    unsigned short pb[4][4];
#pragma unroll
    for (int f = 0; f < 4; ++f)
#pragma unroll
      for (int r = 0; r < 4; ++r) {
        const float p = __expf(sacc[f][r] - mnew);
        psum += p;
        pb[f][r] = f2b(p);
      }
    psum += __shfl_xor(psum, 16);
    psum += __shfl_xor(psum, 32);
    l_run = l_run * alpha + psum;
    m_run = mnew;
#pragma unroll
    for (int f = 0; f < 4; ++f) {
      oacc[f][0] *= alpha; oacc[f][1] *= alpha;
      oacc[f][2] *= alpha; oacc[f][3] *= alpha;
    }
#pragma unroll
    for (int f = 0; f < 4; ++f) {
      us4 pk = { pb[f][0], pb[f][1], pb[f][2], pb[f][3] };
      *(us4*)(sP[wv] + l15 * KP + f * 16 + lg * 4) = pk;
    }
    __syncthreads();

#pragma unroll
    for (int kk = 0; kk < 2; ++kk) {
      sh8 bp = *(const sh8*)(sP[wv] + l15 * KP + kk * 32 + lg * 8);
#pragma unroll
      for (int fe = 0; fe < 4; ++fe) {
        sh8 av = *(const sh8*)(sVT + (fe * 16 + l15) * KP + kk * 32 + lg * 8);
        oacc[fe] = __builtin_amdgcn_mfma_f32_16x16x32_bf16(av, bp, oacc[fe], 0, 0, 0);
      }
    }
  }

  const int qa = qt * 128 + wv * 16 + l15;
  if (qa < S_) {
    const float inv = 1.f / l_run;
    const size_t orow = ((size_t)b * S_ + qa) * 768 + h * 64;
#pragma unroll
    for (int fe = 0; fe < 4; ++fe) {
      unsigned short pk[4];
#pragma unroll
      for (int r = 0; r < 4; ++r) pk[r] = f2b(oacc[fe][r] * inv);
      *(us4*)(ctx + orow + fe * 16 + lg * 4) = *(us4*)pk;
    }
  }
}

// ---------------------------------------------------------------------------
extern "C" void kernel_launch(void* const* d_in, const int* in_sizes, int n_in,
                              void* d_out, int out_size, void* d_ws, size_t ws_size,
                              hipStream_t stream)
{
  const float* x    = (const float*)d_in[0];
  const float* ln1w = (const float*)d_in[1];
  const float* ln1b = (const float*)d_in[2];
  const float* Wq   = (const float*)d_in[3];
  const float* bq   = (const float*)d_in[4];
  const float* Wk   = (const float*)d_in[5];
  const float* bk   = (const float*)d_in[6];
  const float* Wv   = (const float*)d_in[7];
  const float* bv   = (const float*)d_in[8];
  const float* Wo   = (const float*)d_in[9];
  const float* bo   = (const float*)d_in[10];
  const float* ln2w = (const float*)d_in[11];
  const float* ln2b = (const float*)d_in[12];
  const float* W1   = (const float*)d_in[13];
  const float* b1   = (const float*)d_in[14];
  const float* W2   = (const float*)d_in[15];
  const float* b2   = (const float*)d_in[16];
  float* out = (float*)d_out;
  char* ws = (char*)d_ws;

  unsigned short* wqkvT = (unsigned short*)(ws + 0);          //  3,538,944
  unsigned short* woT   = (unsigned short*)(ws + 3538944);    //  1,179,648
  unsigned short* w1T   = (unsigned short*)(ws + 4718592);    //  4,718,592
  unsigned short* w2T   = (unsigned short*)(ws + 9437184);    //  4,718,592
  float*          biasq = (float*)(ws + 14155776);            //      9,216
  unsigned short* hbf   = (unsigned short*)(ws + 14164992);   // 28,360,704
  unsigned short* qkvb  = (unsigned short*)(ws + 42525696);   // 85,082,112
  unsigned short* ctxb  = (unsigned short*)(ws + 127607808);  // 28,360,704
  unsigned short* mlp1  = qkvb;   // overlays dead qkv+ctx

  packQKV64<<<dim3(12, 12, 3), 256, 0, stream>>>(Wq, Wk, Wv, wqkvT);
  bias_pack<<<9, 256, 0, stream>>>(bq, bk, bv, biasq);
  packT64<<<dim3(12, 12), 256, 0, stream>>>(Wo, woT, 768, 768);
  packT64<<<dim3(48, 12), 256, 0, stream>>>(W1, w1T, 768, 3072);
  packT64<<<dim3(12, 48), 256, 0, stream>>>(W2, w2T, 3072, 768);

  // 145 M-tiles of 128 (M=18464)
  ln_bf16<<<MROWS, 256, 0, stream>>>(x, ln1w, ln1b, hbf);
  gemm128<0><<<145 * 18, 256, 0, stream>>>(hbf, wqkvT, biasq, nullptr, qkvb, nullptr,
                                           MROWS, 2304, 768);
  attn<<<dim3(5, 12, 32), 512, 0, stream>>>(qkvb, ctxb);
  gemm128<1><<<145 * 6, 256, 0, stream>>>(ctxb, woT, bo, x, nullptr, out,
                                          MROWS, 768, 768);
  ln_bf16<<<MROWS, 256, 0, stream>>>(out, ln2w, ln2b, hbf);
  gemm128<2><<<145 * 24, 256, 0, stream>>>(hbf, w1T, b1, nullptr, mlp1, nullptr,
                                           MROWS, 3072, 768);
  gemm128<1><<<145 * 6, 256, 0, stream>>>(mlp1, w2T, b2, out, nullptr, out,
                                          MROWS, 768, 3072);
}

// Round 5
// 473.941 us; speedup vs baseline: 1.1223x; 1.0223x over previous
//
#include <hip/hip_runtime.h>
#include <hip/hip_bf16.h>
#include <stdint.h>

#define B_ 32
#define S_ 577
#define D_ 768
#define H_ 12
#define FF_ 3072
#define MROWS (B_*S_)   // 18464

typedef __attribute__((ext_vector_type(8))) short sh8;
typedef __attribute__((ext_vector_type(4))) float f32x4;
typedef __attribute__((ext_vector_type(4))) unsigned short us4;

static __device__ __forceinline__ unsigned short f2b(float f) {
  __hip_bfloat16 h = __float2bfloat16(f);
  return *reinterpret_cast<unsigned short*>(&h);
}
static __device__ __forceinline__ float b2f(unsigned short u) {
  __hip_bfloat16 h;
  *reinterpret_cast<unsigned short*>(&h) = u;
  return __bfloat162float(h);
}

// Branch-free exact-GELU: 0.5*v*(1+erf(v/sqrt2)) with erf via A&S 7.1.26.
// |err(erf)| <= 1.5e-7 -> ~1e-7 output err, 5 orders below bf16 rounding.
static __device__ __forceinline__ float fast_gelu(float v) {
  const float z = fabsf(v) * 0.70710678118f;
  const float t = __builtin_amdgcn_rcpf(__builtin_fmaf(0.3275911f, z, 1.0f));
  float p = 1.061405429f;
  p = __builtin_fmaf(p, t, -1.453152027f);
  p = __builtin_fmaf(p, t,  1.421413741f);
  p = __builtin_fmaf(p, t, -0.284496736f);
  p = __builtin_fmaf(p, t,  0.254829592f);
  p = p * t;
  const float e = __expf(-z * z);
  const float erf_abs = __builtin_fmaf(-p, e, 1.0f);   // erf(|x|)
  const float erf_v = copysignf(erf_abs, v);
  const float hv = 0.5f * v;
  return __builtin_fmaf(hv, erf_v, hv);                // 0.5v*(1+erf)
}

#define GLOAD_LDS16(gp, lp) \
  __builtin_amdgcn_global_load_lds((const __attribute__((address_space(1))) unsigned int*)(gp), \
                                   (__attribute__((address_space(3))) unsigned int*)(lp), 16, 0, 0)

// ---------------------------------------------------------------------------
// Coalesced transpose-packs: fp32 [K][N] -> bf16 [N][K] via 64x64 LDS tiles
// ---------------------------------------------------------------------------
__global__ __launch_bounds__(256) void packT64(
    const float* __restrict__ src, unsigned short* __restrict__ dst, int K, int N)
{
  __shared__ unsigned short t[64][65];
  const int tid = threadIdx.x;
  const int c = tid & 63, r4 = tid >> 6;
  const int kb = blockIdx.y * 64, nb = blockIdx.x * 64;
#pragma unroll
  for (int p = 0; p < 16; ++p) {
    const int ko = p * 4 + r4;
    t[c][ko] = f2b(src[(size_t)(kb + ko) * N + nb + c]);
  }
  __syncthreads();
#pragma unroll
  for (int p = 0; p < 16; ++p) {
    const int rr = p * 4 + r4;
    dst[(size_t)(nb + rr) * K + kb + c] = t[rr][c];
  }
}

// per-head transpose for Wq/Wk/Wv [H][768][64] -> wT[(which*768+h*64+e)][768]
// Q weights pre-scaled by 1/8 (power of two -> bit-exact exponent shift; the
// attention 1/sqrt(Dh) scale then disappears from the attn kernel).
__global__ __launch_bounds__(256) void packQKV64(
    const float* __restrict__ Wq, const float* __restrict__ Wk, const float* __restrict__ Wv,
    unsigned short* __restrict__ dst)
{
  __shared__ unsigned short t[64][65];
  const int tid = threadIdx.x;
  const int c = tid & 63, r4 = tid >> 6;
  const int kb = blockIdx.x * 64;         // d tile (12)
  const int h = blockIdx.y;               // head (12)
  const int which = blockIdx.z;           // 0:q 1:k 2:v
  const float* src = ((which == 0) ? Wq : (which == 1) ? Wk : Wv) + (size_t)h * 768 * 64;
  const float scl = (which == 0) ? 0.125f : 1.0f;
#pragma unroll
  for (int p = 0; p < 16; ++p) {
    const int ko = p * 4 + r4;
    t[c][ko] = f2b(src[(size_t)(kb + ko) * 64 + c] * scl);
  }
  __syncthreads();
  unsigned short* db = dst + (size_t)(which * 768 + h * 64) * 768;
#pragma unroll
  for (int p = 0; p < 16; ++p) {
    const int rr = p * 4 + r4;            // e
    db[(size_t)rr * 768 + kb + c] = t[rr][c];
  }
}

__global__ __launch_bounds__(256) void bias_pack(
    const float* __restrict__ bq, const float* __restrict__ bk, const float* __restrict__ bv,
    float* __restrict__ biasq)
{
  const int idx = blockIdx.x * 256 + threadIdx.x;
  if (idx < 2304) {
    const int wb = idx / 768, rb = idx - wb * 768;
    const float* bb = (wb == 0) ? bq : (wb == 1) ? bk : bv;
    biasq[idx] = bb[rb] * (wb == 0 ? 0.125f : 1.0f);
  }
}

// ---------------------------------------------------------------------------
// LayerNorm fp32 -> bf16 (one 256-thread block per row of 768)
// ---------------------------------------------------------------------------
__global__ __launch_bounds__(256) void ln_bf16(
    const float* __restrict__ x, const float* __restrict__ w, const float* __restrict__ bse,
    unsigned short* __restrict__ out)
{
  const int row = blockIdx.x;
  const int tid = threadIdx.x;
  const float* xr = x + (size_t)row * 768;
  float v0 = xr[tid], v1 = xr[tid + 256], v2 = xr[tid + 512];
  float s = v0 + v1 + v2;
  float ss = v0 * v0 + v1 * v1 + v2 * v2;
#pragma unroll
  for (int off = 32; off >= 1; off >>= 1) {
    s  += __shfl_xor(s, off);
    ss += __shfl_xor(ss, off);
  }
  __shared__ float red[8];
  const int wv = tid >> 6, ln = tid & 63;
  if (ln == 0) { red[wv] = s; red[wv + 4] = ss; }
  __syncthreads();
  s  = red[0] + red[1] + red[2] + red[3];
  ss = red[4] + red[5] + red[6] + red[7];
  const float mu = s * (1.f / 768.f);
  const float var = ss * (1.f / 768.f) - mu * mu;
  const float rs = rsqrtf(var + 1e-5f);
  unsigned short* orow = out + (size_t)row * 768;
  orow[tid]       = f2b((v0 - mu) * rs * w[tid]       + bse[tid]);
  orow[tid + 256] = f2b((v1 - mu) * rs * w[tid + 256] + bse[tid + 256]);
  orow[tid + 512] = f2b((v2 - mu) * rs * w[tid + 512] + bse[tid + 512]);
}

// ---------------------------------------------------------------------------
// m97-style occupancy-first GEMM: 128x128 tile, BK=64, 256 thr = 4 waves.
// Round 5: strength-reduced staging addresses (8 row pointers precomputed,
// advanced +64/step -> per-K-step addressing is 8 pointer adds, not 8x
// 64-bit mul chains); epilogue bias load + column decomposition hoisted
// (c4/gcol invariant across pp and pass since 256 = 0 mod 32).
// EPI 0: bf16 out.  EPI 1: fp32 out + residual.  EPI 2: bf16 out + GELU.
// ---------------------------------------------------------------------------
template<int EPI>
__global__ __launch_bounds__(256, 3) void gemm128(
    const unsigned short* __restrict__ A, const unsigned short* __restrict__ Bt,
    const float* __restrict__ bias, const float* __restrict__ res,
    unsigned short* __restrict__ obf, float* __restrict__ of32,
    int M, int N, int K)
{
  __shared__ __align__(16) unsigned short sAB[2][128 * 64];  // A, B: 16 KiB each
  const int tid = threadIdx.x;
  const int wid = tid >> 6, ln = tid & 63;
  const int wr = wid >> 1, wc = wid & 1;
  const int l15 = ln & 15, lg = ln >> 4;
  const int l7 = l15 & 7;
  const int uo0 = ((lg) ^ l7) * 8;        // swizzled short-offset, kk=0
  const int uo1 = ((4 + lg) ^ l7) * 8;    // kk=1
  const int srow = ln >> 3;               // 0..7
  const int scol = ((ln & 7) ^ srow) * 8; // inverse-swizzled global col
  const int NT = K >> 6;

  // bijective XCD-chunked tile assignment (m204)
  const int gx = N >> 7;
  const int nwg = gridDim.x;
  const int q = nwg >> 3, r = nwg & 7;
  const int x = blockIdx.x & 7, ii = blockIdx.x >> 3;
  const int wg = (x < r ? x * (q + 1) : r * (q + 1) + (x - r) * q) + ii;
  const int bm = wg / gx, bn = wg - bm * gx;

  const int arow = wr * 64 + l15;
  const int brow = wc * 64 + l15;

  // strength-reduced staging: row pointers computed once, +64 per K-step
  const unsigned short* ap0; const unsigned short* ap1;
  const unsigned short* ap2; const unsigned short* ap3;
  const unsigned short* bp0; const unsigned short* bp1;
  const unsigned short* bp2; const unsigned short* bp3;
  {
    int g0 = bm * 128 + (wid * 4 + 0) * 8 + srow; if (g0 >= M) g0 = M - 1;
    int g1 = bm * 128 + (wid * 4 + 1) * 8 + srow; if (g1 >= M) g1 = M - 1;
    int g2 = bm * 128 + (wid * 4 + 2) * 8 + srow; if (g2 >= M) g2 = M - 1;
    int g3 = bm * 128 + (wid * 4 + 3) * 8 + srow; if (g3 >= M) g3 = M - 1;
    ap0 = A + (size_t)g0 * K + scol; ap1 = A + (size_t)g1 * K + scol;
    ap2 = A + (size_t)g2 * K + scol; ap3 = A + (size_t)g3 * K + scol;
    const int b0 = bn * 128 + (wid * 4 + 0) * 8 + srow;
    bp0 = Bt + (size_t)b0 * K + scol;
    bp1 = bp0 + (size_t)8 * K; bp2 = bp0 + (size_t)16 * K; bp3 = bp0 + (size_t)24 * K;
  }
  unsigned short* const lA = sAB[0] + wid * 4 * 512;
  unsigned short* const lB = sAB[1] + wid * 4 * 512;

  f32x4 acc[4][4] = {};

  for (int t = 0; t < NT; ++t) {
    __syncthreads();   // all waves done reading previous tile
    GLOAD_LDS16(ap0, lA);        GLOAD_LDS16(ap1, lA + 512);
    GLOAD_LDS16(ap2, lA + 1024); GLOAD_LDS16(ap3, lA + 1536);
    GLOAD_LDS16(bp0, lB);        GLOAD_LDS16(bp1, lB + 512);
    GLOAD_LDS16(bp2, lB + 1024); GLOAD_LDS16(bp3, lB + 1536);
    ap0 += 64; ap1 += 64; ap2 += 64; ap3 += 64;
    bp0 += 64; bp1 += 64; bp2 += 64; bp3 += 64;
    asm volatile("s_waitcnt vmcnt(0)" ::: "memory");
    __syncthreads();

#pragma unroll
    for (int kk = 0; kk < 2; ++kk) {
      const int uo = kk ? uo1 : uo0;
      sh8 af[4], bf[4];
#pragma unroll
      for (int mi = 0; mi < 4; ++mi)
        af[mi] = *(const sh8*)(sAB[0] + (arow + mi * 16) * 64 + uo);
#pragma unroll
      for (int ni = 0; ni < 4; ++ni)
        bf[ni] = *(const sh8*)(sAB[1] + (brow + ni * 16) * 64 + uo);
#pragma unroll
      for (int mi = 0; mi < 4; ++mi)
#pragma unroll
        for (int ni = 0; ni < 4; ++ni)
          acc[mi][ni] = __builtin_amdgcn_mfma_f32_16x16x32_bf16(af[mi], bf[ni], acc[mi][ni], 0, 0, 0);
    }
  }

  // ---- LDS-staged coalesced epilogue: 4 passes of 32 rows ----
  constexpr int ESTR = 132;               // f32 stride: 16B-aligned, bank-spread
  float* eps = (float*)sAB;               // 32*132*4 = 16,896 B <= 32,768
  const int ecol = (tid & 31) * 4;        // col invariant across pp/pass
  const int gcol = bn * 128 + ecol;
  const f32x4 bvh = *(const f32x4*)(bias + gcol);
  const int erow0 = tid >> 5;             // 0..7
#pragma unroll
  for (int pass = 0; pass < 4; ++pass) {
    __syncthreads();
    if (wr == (pass >> 1)) {
      const int mib = (pass & 1) * 2;
#pragma unroll
      for (int ml = 0; ml < 2; ++ml)
#pragma unroll
        for (int ni = 0; ni < 4; ++ni)
#pragma unroll
          for (int rr = 0; rr < 4; ++rr)
            eps[(ml * 16 + lg * 4 + rr) * ESTR + wc * 64 + ni * 16 + l15] = acc[mib + ml][ni][rr];
    }
    __syncthreads();
#pragma unroll
    for (int pp = 0; pp < 4; ++pp) {
      const int rl = pp * 8 + erow0;      // 0..31
      const int grow = bm * 128 + pass * 32 + rl;
      if (grow < M) {
        f32x4 v = *(const f32x4*)(eps + rl * ESTR + ecol);
        v += bvh;
        if (EPI == 2) {
#pragma unroll
          for (int e = 0; e < 4; ++e) v[e] = fast_gelu(v[e]);
        }
        if (EPI == 1) {
          const f32x4 rv = *(const f32x4*)(res + (size_t)grow * N + gcol);
          v += rv;
          *(f32x4*)(of32 + (size_t)grow * N + gcol) = v;
        } else {
          us4 o = { f2b(v[0]), f2b(v[1]), f2b(v[2]), f2b(v[3]) };
          *(us4*)(obf + (size_t)grow * N + gcol) = o;
        }
      }
    }
  }
}

// ---------------------------------------------------------------------------
// Flash attention, VALU-thinned: QBLK=128 (8 waves, 512 thr), tail-tile
// specialization, Q pre-scaled, strength-reduced K/V staging pointers.
// LDS: sQ 128*72 + sK 64*72 + sVT 64*72 + sP 8*16*72 = 55,296 B -> 2 blk/CU.
// ---------------------------------------------------------------------------
__global__ __launch_bounds__(512) void attn(
    const unsigned short* __restrict__ qkv, unsigned short* __restrict__ ctx)
{
  constexpr int KP = 72;
  __shared__ __align__(16) unsigned short sQ[128 * KP];
  __shared__ __align__(16) unsigned short sK[64 * KP];
  __shared__ __align__(16) unsigned short sVT[64 * KP];
  __shared__ __align__(16) unsigned short sP[8][16 * KP];
  const int tid = threadIdx.x, wv = tid >> 6, ln = tid & 63;
  const int l15 = ln & 15, lg = ln >> 4;
  const int b = blockIdx.z, h = blockIdx.y, qt = blockIdx.x;
  const size_t base = (size_t)b * S_ * 2304 + h * 64;
  const unsigned short* qp = qkv + base;
  const unsigned short* kp = qkv + base + 768;
  const unsigned short* vp = qkv + base + 1536;

  // Q staging: pure copy (weights pre-scaled by 1/8 in pack)
  {
    const int r = tid >> 2, c = (tid & 3) * 16;
    int row = qt * 128 + r; if (row >= S_) row = S_ - 1;
    const unsigned short* g = qp + (size_t)row * 2304 + c;
    *(sh8*)(sQ + r * KP + c)     = *(const sh8*)g;
    *(sh8*)(sQ + r * KP + c + 8) = *(const sh8*)(g + 8);
  }

  // strength-reduced fast-path staging pointers (+64*2304 per tile)
  const int kr = tid >> 3, kc = (tid & 7) * 8;
  const unsigned short* krow = kp + (size_t)kr * 2304 + kc;
  unsigned short* const sKdst = sK + kr * KP + kc;
  const int ve = tid & 63, vkvb = tid >> 6;
  const unsigned short* vrow = vp + (size_t)vkvb * 8 * 2304 + ve;
  unsigned short* const sVdst = sVT + ve * KP + vkvb * 8;

  f32x4 oacc[4] = {};
  float m_run = -1e30f, l_run = 0.f;
  const int nt = (S_ + 63) / 64;          // 10; tiles 0..8 are full
  for (int t = 0; t < nt; ++t) {
    __syncthreads();
    if (t < nt - 1) {
      // fast staging: no row clamps (t*64+63 <= 575 < 577)
      *(sh8*)sKdst = *(const sh8*)krow;
      krow += (size_t)64 * 2304;
      {
        unsigned short val[8];
#pragma unroll
        for (int j = 0; j < 8; ++j) val[j] = vrow[(size_t)j * 2304];
        *(sh8*)sVdst = *(sh8*)val;
        vrow += (size_t)64 * 2304;
      }
    } else {
      {
        int row = t * 64 + kr; if (row >= S_) row = S_ - 1;
        *(sh8*)sKdst = *(const sh8*)(kp + (size_t)row * 2304 + kc);
      }
      {
        unsigned short val[8];
#pragma unroll
        for (int j = 0; j < 8; ++j) {
          int row = t * 64 + vkvb * 8 + j; if (row >= S_) row = S_ - 1;
          val[j] = vp[(size_t)row * 2304 + ve];
        }
        *(sh8*)sVdst = *(sh8*)val;
      }
    }
    __syncthreads();

    f32x4 sacc[4] = {};
#pragma unroll
    for (int kk = 0; kk < 2; ++kk) {
      sh8 bq = *(const sh8*)(sQ + (wv * 16 + l15) * KP + kk * 32 + lg * 8);
#pragma unroll
      for (int f = 0; f < 4; ++f) {
        sh8 ak = *(const sh8*)(sK + (f * 16 + l15) * KP + kk * 32 + lg * 8);
        sacc[f] = __builtin_amdgcn_mfma_f32_16x16x32_bf16(ak, bq, sacc[f], 0, 0, 0);
      }
    }

    if (t == nt - 1) {
#pragma unroll
      for (int f = 0; f < 4; ++f)
#pragma unroll
        for (int r = 0; r < 4; ++r)
          if (t * 64 + f * 16 + lg * 4 + r >= S_) sacc[f][r] = -1e30f;
    }
    float pmax = -1e30f;
#pragma unroll
    for (int f = 0; f < 4; ++f)
#pragma unroll
      for (int r = 0; r < 4; ++r) pmax = fmaxf(pmax, sacc[f][r]);
    pmax = fmaxf(pmax, __shfl_xor(pmax, 16));
    pmax = fmaxf(pmax, __shfl_xor(pmax, 32));
    const float mnew = fmaxf(m_run, pmax);
    const float alpha = __expf(m_run - mnew);
    float psum = 0.f;
    unsigned short pb[4][4];
#pragma unroll
    for (int f = 0; f < 4; ++f)
#pragma unroll
      for (int r = 0; r < 4; ++r) {
        const float p = __expf(sacc[f][r] - mnew);
        psum += p;
        pb[f][r] = f2b(p);
      }
    psum += __shfl_xor(psum, 16);
    psum += __shfl_xor(psum, 32);
    l_run = l_run * alpha + psum;
    m_run = mnew;
#pragma unroll
    for (int f = 0; f < 4; ++f) {
      oacc[f][0] *= alpha; oacc[f][1] *= alpha;
      oacc[f][2] *= alpha; oacc[f][3] *= alpha;
    }
#pragma unroll
    for (int f = 0; f < 4; ++f) {
      us4 pk = { pb[f][0], pb[f][1], pb[f][2], pb[f][3] };
      *(us4*)(sP[wv] + l15 * KP + f * 16 + lg * 4) = pk;
    }
    __syncthreads();

#pragma unroll
    for (int kk = 0; kk < 2; ++kk) {
      sh8 bp = *(const sh8*)(sP[wv] + l15 * KP + kk * 32 + lg * 8);
#pragma unroll
      for (int fe = 0; fe < 4; ++fe) {
        sh8 av = *(const sh8*)(sVT + (fe * 16 + l15) * KP + kk * 32 + lg * 8);
        oacc[fe] = __builtin_amdgcn_mfma_f32_16x16x32_bf16(av, bp, oacc[fe], 0, 0, 0);
      }
    }
  }

  const int qa = qt * 128 + wv * 16 + l15;
  if (qa < S_) {
    const float inv = 1.f / l_run;
    const size_t orow = ((size_t)b * S_ + qa) * 768 + h * 64;
#pragma unroll
    for (int fe = 0; fe < 4; ++fe) {
      unsigned short pk[4];
#pragma unroll
      for (int r = 0; r < 4; ++r) pk[r] = f2b(oacc[fe][r] * inv);
      *(us4*)(ctx + orow + fe * 16 + lg * 4) = *(us4*)pk;
    }
  }
}

// ---------------------------------------------------------------------------
extern "C" void kernel_launch(void* const* d_in, const int* in_sizes, int n_in,
                              void* d_out, int out_size, void* d_ws, size_t ws_size,
                              hipStream_t stream)
{
  const float* x    = (const float*)d_in[0];
  const float* ln1w = (const float*)d_in[1];
  const float* ln1b = (const float*)d_in[2];
  const float* Wq   = (const float*)d_in[3];
  const float* bq   = (const float*)d_in[4];
  const float* Wk   = (const float*)d_in[5];
  const float* bk   = (const float*)d_in[6];
  const float* Wv   = (const float*)d_in[7];
  const float* bv   = (const float*)d_in[8];
  const float* Wo   = (const float*)d_in[9];
  const float* bo   = (const float*)d_in[10];
  const float* ln2w = (const float*)d_in[11];
  const float* ln2b = (const float*)d_in[12];
  const float* W1   = (const float*)d_in[13];
  const float* b1   = (const float*)d_in[14];
  const float* W2   = (const float*)d_in[15];
  const float* b2   = (const float*)d_in[16];
  float* out = (float*)d_out;
  char* ws = (char*)d_ws;

  unsigned short* wqkvT = (unsigned short*)(ws + 0);          //  3,538,944
  unsigned short* woT   = (unsigned short*)(ws + 3538944);    //  1,179,648
  unsigned short* w1T   = (unsigned short*)(ws + 4718592);    //  4,718,592
  unsigned short* w2T   = (unsigned short*)(ws + 9437184);    //  4,718,592
  float*          biasq = (float*)(ws + 14155776);            //      9,216
  unsigned short* hbf   = (unsigned short*)(ws + 14164992);   // 28,360,704
  unsigned short* qkvb  = (unsigned short*)(ws + 42525696);   // 85,082,112
  unsigned short* ctxb  = (unsigned short*)(ws + 127607808);  // 28,360,704
  unsigned short* mlp1  = qkvb;   // overlays dead qkv+ctx

  packQKV64<<<dim3(12, 12, 3), 256, 0, stream>>>(Wq, Wk, Wv, wqkvT);
  bias_pack<<<9, 256, 0, stream>>>(bq, bk, bv, biasq);
  packT64<<<dim3(12, 12), 256, 0, stream>>>(Wo, woT, 768, 768);
  packT64<<<dim3(48, 12), 256, 0, stream>>>(W1, w1T, 768, 3072);
  packT64<<<dim3(12, 48), 256, 0, stream>>>(W2, w2T, 3072, 768);

  // 145 M-tiles of 128 (M=18464)
  ln_bf16<<<MROWS, 256, 0, stream>>>(x, ln1w, ln1b, hbf);
  gemm128<0><<<145 * 18, 256, 0, stream>>>(hbf, wqkvT, biasq, nullptr, qkvb, nullptr,
                                           MROWS, 2304, 768);
  attn<<<dim3(5, 12, 32), 512, 0, stream>>>(qkvb, ctxb);
  gemm128<1><<<145 * 6, 256, 0, stream>>>(ctxb, woT, bo, x, nullptr, out,
                                          MROWS, 768, 768);
  ln_bf16<<<MROWS, 256, 0, stream>>>(out, ln2w, ln2b, hbf);
  gemm128<2><<<145 * 24, 256, 0, stream>>>(hbf, w1T, b1, nullptr, mlp1, nullptr,
                                           MROWS, 3072, 768);
  gemm128<1><<<145 * 6, 256, 0, stream>>>(mlp1, w2T, b2, out, nullptr, out,
                                          MROWS, 768, 3072);
}